// Round 5
// baseline (115.298 us; speedup 1.0000x reference)
//
#include <hip/hip_runtime.h>
#include <math.h>

namespace {
constexpr int S = 64;
constexpr int NP = 131072;
constexpr int H = 32;
constexpr int BLK = 256;
constexpr int NB = NP / BLK;       // 512
constexpr int CH = 128;            // points per k_main block (2 per lane)
constexpr int NCHUNK = 20;         // 20*128 = 2560 >= max cell count (~2160)

// d_ws layout (ints):
constexpr int WS_HIST = 0;                  // [0,64)
constexpr int WS_OFF  = 64;                 // [64,128)
constexpr int WS_CUR  = 128;                // [128,192)
constexpr int WS_CELL = 192;                // [192, 192+NP)
constexpr int WS_LIST = WS_CELL + NP;       // [+NP)
constexpr int WS_XS   = WS_LIST + NP;       // float2[NP] -> 2*NP ints

__device__ __forceinline__ float dev_exp2(float v) {
    return __builtin_amdgcn_exp2f(v);       // v_exp_f32: 2^v, saturates to inf/0
}
__device__ __forceinline__ float fast_tanh(float v) {
    // tanh(v) = 1 - 2/(e^{2v}+1); exp2 overflow/underflow gives exact +-1 saturation
    float e = dev_exp2(v * 2.8853900817779268f);
    return 1.0f - __fdividef(2.0f, e + 1.0f);
}
__device__ __forceinline__ float fast_sigmoid(float z) {
    return __fdividef(1.0f, 1.0f + dev_exp2(z * -1.4426950408889634f));
}
__device__ __forceinline__ int cell_of(float xx) {
    int c = (int)floorf((xx + 1.0f) * 32.0f);
    return min(S - 1, max(0, c));
}

__global__ void k_zero(int* hist) { hist[threadIdx.x] = 0; }

__global__ __launch_bounds__(BLK) void k_hist(const float* __restrict__ x,
                                              int* __restrict__ hist,
                                              int* __restrict__ cell) {
    __shared__ int lh[S];
    const int tid = threadIdx.x;
    if (tid < S) lh[tid] = 0;
    __syncthreads();
    const int p = blockIdx.x * BLK + tid;
    const int c = cell_of(x[2 * p + 1]);
    cell[p] = c;
    atomicAdd(&lh[c], 1);
    __syncthreads();
    if (tid < S && lh[tid] != 0) atomicAdd(&hist[tid], lh[tid]);
}

__global__ __launch_bounds__(S) void k_off(const int* __restrict__ hist,
                                           int* __restrict__ off,
                                           int* __restrict__ cursor) {
    const int t = threadIdx.x;
    int v = hist[t];
    int sum = v;
    #pragma unroll
    for (int d = 1; d < 64; d <<= 1) {
        int o = __shfl_up(sum, d);
        if (t >= d) sum += o;
    }
    off[t] = sum - v;
    cursor[t] = sum - v;
}

__global__ __launch_bounds__(BLK) void k_scatter(const float* __restrict__ x,
                                                 const int* __restrict__ cell,
                                                 int* __restrict__ cursor,
                                                 int* __restrict__ list,
                                                 float2* __restrict__ xsorted) {
    __shared__ int lh[S];
    __shared__ int lbase[S];
    const int tid = threadIdx.x;
    if (tid < S) lh[tid] = 0;
    __syncthreads();
    const int p = blockIdx.x * BLK + tid;
    const int c = cell[p];
    const int r = atomicAdd(&lh[c], 1);
    __syncthreads();
    if (tid < S && lh[tid] != 0) lbase[tid] = atomicAdd(&cursor[tid], lh[tid]);
    __syncthreads();
    const int pos = lbase[c] + r;
    list[pos] = p;
    xsorted[pos] = ((const float2*)x)[p];
}

// block = 192 threads = 3 waves; wave w evaluates subnet j=c-1+w for 128 points (2/lane)
__global__ __launch_bounds__(192, 3) void k_main(
    const float2* __restrict__ xsorted,
    const float* __restrict__ lo_core, const float* __restrict__ hi_core,
    const float* __restrict__ lo_ext,  const float* __restrict__ hi_ext,
    const float* __restrict__ W_in,  const float* __restrict__ b_in,
    const float* __restrict__ W_h1,  const float* __restrict__ b_h1,
    const float* __restrict__ W_h2,  const float* __restrict__ b_h2,
    const float* __restrict__ W_out, const float* __restrict__ b_out,
    const int* __restrict__ hist, const int* __restrict__ off,
    const int* __restrict__ list,
    float* __restrict__ out)
{
    const int c   = blockIdx.x;
    const int cnt = hist[c];
    const int base = blockIdx.y * CH;
    if (base >= cnt) return;

    const int wid  = threadIdx.x >> 6;           // 0..2
    const int lane = threadIdx.x & 63;
    const int o = off[c];
    const int idx0 = base + lane;
    const int idx1 = base + lane + 64;
    const bool act0 = idx0 < cnt;
    const bool act1 = idx1 < cnt;
    const int slot0 = o + (act0 ? idx0 : cnt - 1);
    const int slot1 = o + (act1 ? idx1 : cnt - 1);
    const float2 xv0 = xsorted[slot0];
    const float2 xv1 = xsorted[slot1];
    const float tt0 = xv0.x, xx0 = xv0.y;
    const float tt1 = xv1.x, xx1 = xv1.y;

    __shared__ float lnum[3][CH];
    __shared__ float lden[3][CH];

    float num0 = 0.0f, den0 = 0.0f, num1 = 0.0f, den1 = 0.0f;
    const int j = c - 1 + wid;
    if (j >= 0 && j < S) {                        // wave-uniform
        const int ju = __builtin_amdgcn_readfirstlane(j);
        const float le0 = lo_ext[2*ju+0], he0 = hi_ext[2*ju+0];
        const float le1 = lo_ext[2*ju+1], he1 = hi_ext[2*ju+1];
        const float ic0 = (le0 + he0) * 0.5f, ih0 = __fdividef(1.0f, (he0 - le0) * 0.5f);
        const float ic1 = (le1 + he1) * 0.5f, ih1 = __fdividef(1.0f, (he1 - le1) * 0.5f);
        const float xnA0 = (tt0 - ic0) * ih0, xnA1 = (xx0 - ic1) * ih1;
        const float xnB0 = (tt1 - ic0) * ih0, xnB1 = (xx1 - ic1) * ih1;

        const float* Wi = W_in + ju * (H * 2);
        const float* bi = b_in + ju * H;
        float hA0[H], hB0[H], hA1[H], hB1[H];
        #pragma unroll
        for (int k = 0; k < H; ++k) {
            const float w0 = Wi[2*k], w1 = Wi[2*k+1], b = bi[k];
            hA0[k] = fast_tanh(fmaf(xnA1, w1, fmaf(xnA0, w0, b)));
            hB0[k] = fast_tanh(fmaf(xnB1, w1, fmaf(xnB0, w0, b)));
        }
        const float* W1 = W_h1 + ju * (H * H);
        const float* b1 = b_h1 + ju * H;
        #pragma unroll 4
        for (int k = 0; k < H; ++k) {
            float a0 = b1[k], a1 = a0;
            #pragma unroll
            for (int q = 0; q < H; ++q) {
                const float w = W1[k*H+q];
                a0 = fmaf(hA0[q], w, a0);
                a1 = fmaf(hB0[q], w, a1);
            }
            hA1[k] = fast_tanh(a0);
            hB1[k] = fast_tanh(a1);
        }
        const float* W2 = W_h2 + ju * (H * H);
        const float* b2 = b_h2 + ju * H;
        #pragma unroll 4
        for (int k = 0; k < H; ++k) {
            float a0 = b2[k], a1 = a0;
            #pragma unroll
            for (int q = 0; q < H; ++q) {
                const float w = W2[k*H+q];
                a0 = fmaf(hA1[q], w, a0);
                a1 = fmaf(hB1[q], w, a1);
            }
            hA0[k] = fast_tanh(a0);               // reuse layer-1 arrays
            hB0[k] = fast_tanh(a1);
        }
        const float* Wo = W_out + ju * H;
        float acc0 = b_out[ju], acc1 = acc0;
        #pragma unroll
        for (int q = 0; q < H; ++q) {
            const float w = Wo[q];
            acc0 = fmaf(hA0[q], w, acc0);
            acc1 = fmaf(hB0[q], w, acc1);
        }

        float w0 = 1.0f, w1 = 1.0f;
        {
            const float lc = lo_core[2*ju+0], hc = hi_core[2*ju+0];
            const float ov = fmaxf(he0 - hc, lc - le0);
            const float sc = __fdividef(4.0f, fmaf(2.0f * ov, he0 - le0, 1e-8f));
            w0 *= fast_sigmoid(sc * (tt0 - lc)) * fast_sigmoid(sc * (hc - tt0));
            w1 *= fast_sigmoid(sc * (tt1 - lc)) * fast_sigmoid(sc * (hc - tt1));
        }
        {
            const float lc = lo_core[2*ju+1], hc = hi_core[2*ju+1];
            const float ov = fmaxf(he1 - hc, lc - le1);
            const float sc = __fdividef(4.0f, fmaf(2.0f * ov, he1 - le1, 1e-8f));
            w0 *= fast_sigmoid(sc * (xx0 - lc)) * fast_sigmoid(sc * (hc - xx0));
            w1 *= fast_sigmoid(sc * (xx1 - lc)) * fast_sigmoid(sc * (hc - xx1));
        }
        num0 = acc0 * w0; den0 = w0;
        num1 = acc1 * w1; den1 = w1;
    }
    lnum[wid][lane]      = num0;
    lnum[wid][lane + 64] = num1;
    lden[wid][lane]      = den0;
    lden[wid][lane + 64] = den1;
    __syncthreads();

    // wave0 lane l finalizes point l (its pt0); wave1 lane l finalizes point 64+l (its pt1)
    if (wid < 2) {
        const int   pi    = wid * 64 + lane;
        const bool  act   = wid == 0 ? act0  : act1;
        const float ttF   = wid == 0 ? tt0   : tt1;
        const float xxF   = wid == 0 ? xx0   : xx1;
        const int   slotF = wid == 0 ? slot0 : slot1;
        if (act) {
            const float nsum = lnum[0][pi] + lnum[1][pi] + lnum[2][pi];
            const float dsum = lden[0][pi] + lden[1][pi] + lden[2][pi];
            const float u = __fdividef(nsum, dsum + 1e-8f);
            const float g = -sinf(3.14159265358979323846f * xxF);
            const float factor = fast_tanh(xxF + 1.0f) * fast_tanh(xxF - 1.0f) * fast_tanh(ttF);
            out[list[slotF]] = fmaf(factor, u, g);
        }
    }
}
} // namespace

extern "C" void kernel_launch(void* const* d_in, const int* in_sizes, int n_in,
                              void* d_out, int out_size, void* d_ws, size_t ws_size,
                              hipStream_t stream) {
    const float* x       = (const float*)d_in[0];
    const float* lo_core = (const float*)d_in[1];
    const float* hi_core = (const float*)d_in[2];
    const float* lo_ext  = (const float*)d_in[3];
    const float* hi_ext  = (const float*)d_in[4];
    const float* W_in    = (const float*)d_in[5];
    const float* b_in    = (const float*)d_in[6];
    const float* W_h1    = (const float*)d_in[7];
    const float* b_h1    = (const float*)d_in[8];
    const float* W_h2    = (const float*)d_in[9];
    const float* b_h2    = (const float*)d_in[10];
    const float* W_out   = (const float*)d_in[11];
    const float* b_out   = (const float*)d_in[12];
    float* out = (float*)d_out;

    int* ws      = (int*)d_ws;
    int* hist    = ws + WS_HIST;
    int* off     = ws + WS_OFF;
    int* cursor  = ws + WS_CUR;
    int* cell    = ws + WS_CELL;
    int* list    = ws + WS_LIST;
    float2* xsorted = (float2*)(ws + WS_XS);

    hipLaunchKernelGGL(k_zero,    dim3(1),          dim3(S),   0, stream, hist);
    hipLaunchKernelGGL(k_hist,    dim3(NB),         dim3(BLK), 0, stream, x, hist, cell);
    hipLaunchKernelGGL(k_off,     dim3(1),          dim3(S),   0, stream, hist, off, cursor);
    hipLaunchKernelGGL(k_scatter, dim3(NB),         dim3(BLK), 0, stream, x, cell, cursor, list, xsorted);
    hipLaunchKernelGGL(k_main,    dim3(S, NCHUNK),  dim3(192), 0, stream,
        xsorted, lo_core, hi_core, lo_ext, hi_ext, W_in, b_in, W_h1, b_h1,
        W_h2, b_h2, W_out, b_out, hist, off, list, out);
}

// Round 6
// 94.355 us; speedup vs baseline: 1.2220x; 1.2220x over previous
//
#include <hip/hip_runtime.h>
#include <math.h>

namespace {
constexpr int S = 64;
constexpr int NP = 131072;
constexpr int H = 32;
constexpr int BLK = 256;
constexpr int NB = NP / BLK;       // 512
constexpr int CH = 128;            // points per k_main block (2 per lane)
constexpr int NCHUNK = 20;         // 20*128 = 2560 >= max cell count (~2160)

// d_ws layout (ints):
constexpr int WS_HIST = 0;                  // [0,64)
constexpr int WS_OFF  = 64;                 // [64,128)
constexpr int WS_CUR  = 128;                // [128,192)
constexpr int WS_CELL = 192;                // [192, 192+NP)
constexpr int WS_LIST = WS_CELL + NP;       // [+NP)
constexpr int WS_XS   = WS_LIST + NP;       // float2[NP] -> 2*NP ints

__device__ __forceinline__ float dev_exp2(float v) {
    return __builtin_amdgcn_exp2f(v);       // v_exp_f32: 2^v, saturates to inf/0
}
__device__ __forceinline__ float fast_tanh(float v) {
    // tanh(v) = 1 - 2/(e^{2v}+1); exp2 overflow/underflow gives exact +-1 saturation
    float e = dev_exp2(v * 2.8853900817779268f);
    return 1.0f - __fdividef(2.0f, e + 1.0f);
}
__device__ __forceinline__ float fast_sigmoid(float z) {
    return __fdividef(1.0f, 1.0f + dev_exp2(z * -1.4426950408889634f));
}
__device__ __forceinline__ int cell_of(float xx) {
    int c = (int)floorf((xx + 1.0f) * 32.0f);
    return min(S - 1, max(0, c));
}

__global__ void k_zero(int* hist) { hist[threadIdx.x] = 0; }

__global__ __launch_bounds__(BLK) void k_hist(const float* __restrict__ x,
                                              int* __restrict__ hist,
                                              int* __restrict__ cell) {
    __shared__ int lh[S];
    const int tid = threadIdx.x;
    if (tid < S) lh[tid] = 0;
    __syncthreads();
    const int p = blockIdx.x * BLK + tid;
    const int c = cell_of(x[2 * p + 1]);
    cell[p] = c;
    atomicAdd(&lh[c], 1);
    __syncthreads();
    if (tid < S && lh[tid] != 0) atomicAdd(&hist[tid], lh[tid]);
}

__global__ __launch_bounds__(S) void k_off(const int* __restrict__ hist,
                                           int* __restrict__ off,
                                           int* __restrict__ cursor) {
    const int t = threadIdx.x;
    int v = hist[t];
    int sum = v;
    #pragma unroll
    for (int d = 1; d < 64; d <<= 1) {
        int o = __shfl_up(sum, d);
        if (t >= d) sum += o;
    }
    off[t] = sum - v;
    cursor[t] = sum - v;
}

__global__ __launch_bounds__(BLK) void k_scatter(const float* __restrict__ x,
                                                 const int* __restrict__ cell,
                                                 int* __restrict__ cursor,
                                                 int* __restrict__ list,
                                                 float2* __restrict__ xsorted) {
    __shared__ int lh[S];
    __shared__ int lbase[S];
    const int tid = threadIdx.x;
    if (tid < S) lh[tid] = 0;
    __syncthreads();
    const int p = blockIdx.x * BLK + tid;
    const int c = cell[p];
    const int r = atomicAdd(&lh[c], 1);
    __syncthreads();
    if (tid < S && lh[tid] != 0) lbase[tid] = atomicAdd(&cursor[tid], lh[tid]);
    __syncthreads();
    const int pos = lbase[c] + r;
    list[pos] = p;
    xsorted[pos] = ((const float2*)x)[p];
}

// block = 192 threads = 3 waves; wave w evaluates subnet j=c-1+w for 128 points (2/lane)
// ALL neuron loops fully unrolled: every h-array index is compile-time (rule #20).
__global__ __launch_bounds__(192, 3) void k_main(
    const float2* __restrict__ xsorted,
    const float* __restrict__ lo_core, const float* __restrict__ hi_core,
    const float* __restrict__ lo_ext,  const float* __restrict__ hi_ext,
    const float* __restrict__ W_in,  const float* __restrict__ b_in,
    const float* __restrict__ W_h1,  const float* __restrict__ b_h1,
    const float* __restrict__ W_h2,  const float* __restrict__ b_h2,
    const float* __restrict__ W_out, const float* __restrict__ b_out,
    const int* __restrict__ hist, const int* __restrict__ off,
    const int* __restrict__ list,
    float* __restrict__ out)
{
    const int c   = blockIdx.x;
    const int cnt = hist[c];
    const int base = blockIdx.y * CH;
    if (base >= cnt) return;

    const int wid  = threadIdx.x >> 6;           // 0..2
    const int lane = threadIdx.x & 63;
    const int o = off[c];
    const int idx0 = base + lane;
    const int idx1 = base + lane + 64;
    const bool act0 = idx0 < cnt;
    const bool act1 = idx1 < cnt;
    const int slot0 = o + (act0 ? idx0 : cnt - 1);
    const int slot1 = o + (act1 ? idx1 : cnt - 1);
    const float2 xv0 = xsorted[slot0];
    const float2 xv1 = xsorted[slot1];
    const float tt0 = xv0.x, xx0 = xv0.y;
    const float tt1 = xv1.x, xx1 = xv1.y;

    __shared__ float lnum[3][CH];
    __shared__ float lden[3][CH];

    float num0 = 0.0f, den0 = 0.0f, num1 = 0.0f, den1 = 0.0f;
    const int j = c - 1 + wid;
    if (j >= 0 && j < S) {                        // wave-uniform
        const int ju = __builtin_amdgcn_readfirstlane(j);
        const float le0 = lo_ext[2*ju+0], he0 = hi_ext[2*ju+0];
        const float le1 = lo_ext[2*ju+1], he1 = hi_ext[2*ju+1];
        const float ic0 = (le0 + he0) * 0.5f, ih0 = __fdividef(1.0f, (he0 - le0) * 0.5f);
        const float ic1 = (le1 + he1) * 0.5f, ih1 = __fdividef(1.0f, (he1 - le1) * 0.5f);
        const float xnA0 = (tt0 - ic0) * ih0, xnA1 = (xx0 - ic1) * ih1;
        const float xnB0 = (tt1 - ic0) * ih0, xnB1 = (xx1 - ic1) * ih1;

        const float* Wi = W_in + ju * (H * 2);
        const float* bi = b_in + ju * H;
        float hA0[H], hB0[H], hA1[H], hB1[H];
        #pragma unroll
        for (int k = 0; k < H; ++k) {
            const float w0 = Wi[2*k], w1 = Wi[2*k+1], b = bi[k];
            hA0[k] = fast_tanh(fmaf(xnA1, w1, fmaf(xnA0, w0, b)));
            hB0[k] = fast_tanh(fmaf(xnB1, w1, fmaf(xnB0, w0, b)));
        }
        const float* W1 = W_h1 + ju * (H * H);
        const float* b1 = b_h1 + ju * H;
        #pragma unroll
        for (int k = 0; k < H; ++k) {
            float a0 = b1[k], a1 = a0;
            #pragma unroll
            for (int q = 0; q < H; ++q) {
                const float w = W1[k*H+q];
                a0 = fmaf(hA0[q], w, a0);
                a1 = fmaf(hB0[q], w, a1);
            }
            hA1[k] = fast_tanh(a0);
            hB1[k] = fast_tanh(a1);
        }
        const float* W2 = W_h2 + ju * (H * H);
        const float* b2 = b_h2 + ju * H;
        #pragma unroll
        for (int k = 0; k < H; ++k) {
            float a0 = b2[k], a1 = a0;
            #pragma unroll
            for (int q = 0; q < H; ++q) {
                const float w = W2[k*H+q];
                a0 = fmaf(hA1[q], w, a0);
                a1 = fmaf(hB1[q], w, a1);
            }
            hA0[k] = fast_tanh(a0);               // reuse layer-1 arrays
            hB0[k] = fast_tanh(a1);
        }
        const float* Wo = W_out + ju * H;
        float acc0 = b_out[ju], acc1 = acc0;
        #pragma unroll
        for (int q = 0; q < H; ++q) {
            const float w = Wo[q];
            acc0 = fmaf(hA0[q], w, acc0);
            acc1 = fmaf(hB0[q], w, acc1);
        }

        float w0 = 1.0f, w1 = 1.0f;
        {
            const float lc = lo_core[2*ju+0], hc = hi_core[2*ju+0];
            const float ov = fmaxf(he0 - hc, lc - le0);
            const float sc = __fdividef(4.0f, fmaf(2.0f * ov, he0 - le0, 1e-8f));
            w0 *= fast_sigmoid(sc * (tt0 - lc)) * fast_sigmoid(sc * (hc - tt0));
            w1 *= fast_sigmoid(sc * (tt1 - lc)) * fast_sigmoid(sc * (hc - tt1));
        }
        {
            const float lc = lo_core[2*ju+1], hc = hi_core[2*ju+1];
            const float ov = fmaxf(he1 - hc, lc - le1);
            const float sc = __fdividef(4.0f, fmaf(2.0f * ov, he1 - le1, 1e-8f));
            w0 *= fast_sigmoid(sc * (xx0 - lc)) * fast_sigmoid(sc * (hc - xx0));
            w1 *= fast_sigmoid(sc * (xx1 - lc)) * fast_sigmoid(sc * (hc - xx1));
        }
        num0 = acc0 * w0; den0 = w0;
        num1 = acc1 * w1; den1 = w1;
    }
    lnum[wid][lane]      = num0;
    lnum[wid][lane + 64] = num1;
    lden[wid][lane]      = den0;
    lden[wid][lane + 64] = den1;
    __syncthreads();

    // wave0 lane l finalizes point l (its pt0); wave1 lane l finalizes point 64+l (its pt1)
    if (wid < 2) {
        const int   pi    = wid * 64 + lane;
        const bool  act   = wid == 0 ? act0  : act1;
        const float ttF   = wid == 0 ? tt0   : tt1;
        const float xxF   = wid == 0 ? xx0   : xx1;
        const int   slotF = wid == 0 ? slot0 : slot1;
        if (act) {
            const float nsum = lnum[0][pi] + lnum[1][pi] + lnum[2][pi];
            const float dsum = lden[0][pi] + lden[1][pi] + lden[2][pi];
            const float u = __fdividef(nsum, dsum + 1e-8f);
            const float g = -sinf(3.14159265358979323846f * xxF);
            const float factor = fast_tanh(xxF + 1.0f) * fast_tanh(xxF - 1.0f) * fast_tanh(ttF);
            out[list[slotF]] = fmaf(factor, u, g);
        }
    }
}
} // namespace

extern "C" void kernel_launch(void* const* d_in, const int* in_sizes, int n_in,
                              void* d_out, int out_size, void* d_ws, size_t ws_size,
                              hipStream_t stream) {
    const float* x       = (const float*)d_in[0];
    const float* lo_core = (const float*)d_in[1];
    const float* hi_core = (const float*)d_in[2];
    const float* lo_ext  = (const float*)d_in[3];
    const float* hi_ext  = (const float*)d_in[4];
    const float* W_in    = (const float*)d_in[5];
    const float* b_in    = (const float*)d_in[6];
    const float* W_h1    = (const float*)d_in[7];
    const float* b_h1    = (const float*)d_in[8];
    const float* W_h2    = (const float*)d_in[9];
    const float* b_h2    = (const float*)d_in[10];
    const float* W_out   = (const float*)d_in[11];
    const float* b_out   = (const float*)d_in[12];
    float* out = (float*)d_out;

    int* ws      = (int*)d_ws;
    int* hist    = ws + WS_HIST;
    int* off     = ws + WS_OFF;
    int* cursor  = ws + WS_CUR;
    int* cell    = ws + WS_CELL;
    int* list    = ws + WS_LIST;
    float2* xsorted = (float2*)(ws + WS_XS);

    hipLaunchKernelGGL(k_zero,    dim3(1),          dim3(S),   0, stream, hist);
    hipLaunchKernelGGL(k_hist,    dim3(NB),         dim3(BLK), 0, stream, x, hist, cell);
    hipLaunchKernelGGL(k_off,     dim3(1),          dim3(S),   0, stream, hist, off, cursor);
    hipLaunchKernelGGL(k_scatter, dim3(NB),         dim3(BLK), 0, stream, x, cell, cursor, list, xsorted);
    hipLaunchKernelGGL(k_main,    dim3(S, NCHUNK),  dim3(192), 0, stream,
        xsorted, lo_core, hi_core, lo_ext, hi_ext, W_in, b_in, W_h1, b_h1,
        W_h2, b_h2, W_out, b_out, hist, off, list, out);
}